// Round 1
// baseline (418.529 us; speedup 1.0000x reference)
//
#include <hip/hip_runtime.h>
#include <hip/hip_bf16.h>
#include <math.h>

#define N_NODES 50000
#define N_EDGES 800000
#define IN_F 256
#define HD 128   // H*D
#define NHEAD 4

__device__ __forceinline__ float lrelu(float x){ return x > 0.f ? x : 0.2f * x; }

__global__ void zero_ints(int* __restrict__ p, int n){
    int i = blockIdx.x * blockDim.x + threadIdx.x;
    if (i < n) p[i] = 0;
}

// ---------------- GEMM: ft[N,128] = feat[N,256] @ W[256,128] (f32 vector) ----------------
#define BM 64
#define BK 32
__global__ __launch_bounds__(256) void gemm_kernel(const float* __restrict__ feat,
                                                   const float* __restrict__ W,
                                                   float* __restrict__ ft){
    __shared__ float As[BK][68];    // [k][m], padded for bank spread
    __shared__ float Bs[BK][132];   // [k][n], padded
    const int tid = threadIdx.x;
    const int tx = tid & 15;        // col group
    const int ty = tid >> 4;        // row group
    const int row0 = blockIdx.x * BM;

    float acc[4][8];
#pragma unroll
    for (int i = 0; i < 4; i++)
#pragma unroll
        for (int j = 0; j < 8; j++) acc[i][j] = 0.f;

    const int lr = tid >> 3;          // 0..31
    const int lk = (tid & 7) * 4;     // 0,4,...,28

    for (int kc = 0; kc < IN_F; kc += BK){
        // stage feat tile (64 rows x 32 k), transposed into As[k][m]
#pragma unroll
        for (int rr = 0; rr < 2; rr++){
            int r = lr + rr * 32;
            int gr = row0 + r;
            float4 v = make_float4(0.f, 0.f, 0.f, 0.f);
            if (gr < N_NODES) v = *(const float4*)(feat + (size_t)gr * IN_F + kc + lk);
            As[lk + 0][r] = v.x; As[lk + 1][r] = v.y;
            As[lk + 2][r] = v.z; As[lk + 3][r] = v.w;
        }
        // stage W tile (32 k x 128 cols)
        {
            int kr  = tid >> 3;           // 0..31
            int c16 = (tid & 7) * 16;     // 0..112
            const float* wp = W + (size_t)(kc + kr) * HD + c16;
#pragma unroll
            for (int u = 0; u < 4; u++){
                float4 v = *(const float4*)(wp + 4 * u);
                *(float4*)(&Bs[kr][c16 + 4 * u]) = v;
            }
        }
        __syncthreads();
#pragma unroll
        for (int k = 0; k < BK; k++){
            float4 a  = *(const float4*)(&As[k][ty * 4]);
            float4 b0 = *(const float4*)(&Bs[k][tx * 4]);
            float4 b1 = *(const float4*)(&Bs[k][64 + tx * 4]);
            float av[4] = {a.x, a.y, a.z, a.w};
            float bv[8] = {b0.x, b0.y, b0.z, b0.w, b1.x, b1.y, b1.z, b1.w};
#pragma unroll
            for (int i = 0; i < 4; i++)
#pragma unroll
                for (int j = 0; j < 8; j++)
                    acc[i][j] += av[i] * bv[j];
        }
        __syncthreads();
    }
#pragma unroll
    for (int i = 0; i < 4; i++){
        int gr = row0 + ty * 4 + i;
        if (gr < N_NODES){
            float4 o0 = make_float4(acc[i][0], acc[i][1], acc[i][2], acc[i][3]);
            float4 o1 = make_float4(acc[i][4], acc[i][5], acc[i][6], acc[i][7]);
            *(float4*)(ft + (size_t)gr * HD + tx * 4)      = o0;
            *(float4*)(ft + (size_t)gr * HD + 64 + tx * 4) = o1;
        }
    }
}

// ---------------- per-node attention logits el/er [N,4] ----------------
__global__ __launch_bounds__(128) void attn_kernel(const float* __restrict__ ft,
                                                   const float* __restrict__ attn_l,
                                                   const float* __restrict__ attn_r,
                                                   float* __restrict__ el,
                                                   float* __restrict__ er){
    int n = blockIdx.x;
    int tid = threadIdx.x;          // 0..127, h = tid>>5, d = tid&31
    float v  = ft[(size_t)n * HD + tid];
    float pl = v * attn_l[tid];
    float pr = v * attn_r[tid];
#pragma unroll
    for (int m = 16; m >= 1; m >>= 1){
        pl += __shfl_xor(pl, m, 64);
        pr += __shfl_xor(pr, m, 64);
    }
    if ((tid & 31) == 0){
        el[n * NHEAD + (tid >> 5)] = pl;
        er[n * NHEAD + (tid >> 5)] = pr;
    }
}

// ---------------- CSR build ----------------
__global__ void degree_kernel(const int* __restrict__ dst, int* __restrict__ deg){
    int e = blockIdx.x * blockDim.x + threadIdx.x;
    if (e < N_EDGES) atomicAdd(&deg[dst[e]], 1);
}

__global__ __launch_bounds__(1024) void scan_kernel(const int* __restrict__ deg,
                                                    int* __restrict__ row_off){
    __shared__ int lds[1024];
    __shared__ int carry_s;
    int tid = threadIdx.x;
    if (tid == 0) carry_s = 0;
    __syncthreads();
    for (int base = 0; base < N_NODES; base += 1024){
        int i = base + tid;
        int v = (i < N_NODES) ? deg[i] : 0;
        lds[tid] = v;
        __syncthreads();
        for (int off = 1; off < 1024; off <<= 1){
            int t = (tid >= off) ? lds[tid - off] : 0;
            __syncthreads();
            if (tid >= off) lds[tid] += t;
            __syncthreads();
        }
        int incl  = lds[tid];
        int total = lds[1023];
        int carry = carry_s;
        if (i < N_NODES) row_off[i] = carry + incl - v;   // exclusive
        __syncthreads();
        if (tid == 0) carry_s = carry + total;
        __syncthreads();
    }
    if (tid == 0) row_off[N_NODES] = carry_s;
}

__global__ void scatter_kernel(const int* __restrict__ src, const int* __restrict__ dst,
                               const float* __restrict__ el, const float* __restrict__ er,
                               const int* __restrict__ row_off, int* __restrict__ cursor,
                               int* __restrict__ csr_src, float* __restrict__ w_srt){
    int e = blockIdx.x * blockDim.x + threadIdx.x;
    if (e >= N_EDGES) return;
    int d = dst[e], s = src[e];
    int pos = row_off[d] + atomicAdd(&cursor[d], 1);
    csr_src[pos] = s;
    float4 elv = *(const float4*)(el + (size_t)s * NHEAD);
    float4 erv = *(const float4*)(er + (size_t)d * NHEAD);
    float4 w;
    w.x = __expf(lrelu(elv.x + erv.x));
    w.y = __expf(lrelu(elv.y + erv.y));
    w.z = __expf(lrelu(elv.z + erv.z));
    w.w = __expf(lrelu(elv.w + erv.w));
    *(float4*)(w_srt + (size_t)pos * NHEAD) = w;
}

// ---------------- aggregation: one block per dst node ----------------
__global__ __launch_bounds__(128) void aggregate_kernel(const float* __restrict__ ft,
                                                        const int* __restrict__ csr_src,
                                                        const float* __restrict__ w_srt,
                                                        const int* __restrict__ row_off,
                                                        const float* __restrict__ bias,
                                                        float* __restrict__ out){
    int n   = blockIdx.x;
    int tid = threadIdx.x;      // 0..127 : h = tid>>5
    int h   = tid >> 5;
    int beg = row_off[n], end = row_off[n + 1];
    float acc = 0.f, sacc = 0.f;
    for (int i = beg; i < end; ++i){
        int s   = csr_src[i];
        float w = w_srt[(size_t)i * NHEAD + h];
        acc  += w * ft[(size_t)s * HD + tid];
        sacc += w;
    }
    float o = (end > beg) ? (acc / sacc) : 0.f;
    out[(size_t)n * HD + tid] = o + bias[tid];
}

extern "C" void kernel_launch(void* const* d_in, const int* in_sizes, int n_in,
                              void* d_out, int out_size, void* d_ws, size_t ws_size,
                              hipStream_t stream){
    const float* feat   = (const float*)d_in[0];
    const int*   src    = (const int*)  d_in[1];
    const int*   dst    = (const int*)  d_in[2];
    const float* W      = (const float*)d_in[3];
    const float* attn_l = (const float*)d_in[4];
    const float* attn_r = (const float*)d_in[5];
    const float* bias   = (const float*)d_in[6];
    float* out = (float*)d_out;
    char*  ws  = (char*)d_ws;

    // workspace layout (bytes)
    float* ft      = (float*)(ws + 0);          // 50000*128*4 = 25,600,000
    float* el      = (float*)(ws + 25600000);   // 800,000
    float* er      = (float*)(ws + 26400000);   // 800,000
    int*   deg     = (int*)  (ws + 27200000);   // 200,000
    int*   cursor  = (int*)  (ws + 27400000);   // 200,000 (contiguous after deg)
    int*   row_off = (int*)  (ws + 27600000);   // 200,004 (pad to 200,064)
    int*   csr_src = (int*)  (ws + 27800064);   // 3,200,000
    float* w_srt   = (float*)(ws + 31000064);   // 12,800,000  (total ~43.8 MB)

    zero_ints<<<(2 * N_NODES + 255) / 256, 256, 0, stream>>>(deg, 2 * N_NODES);
    gemm_kernel<<<(N_NODES + BM - 1) / BM, 256, 0, stream>>>(feat, W, ft);
    attn_kernel<<<N_NODES, 128, 0, stream>>>(ft, attn_l, attn_r, el, er);
    degree_kernel<<<(N_EDGES + 255) / 256, 256, 0, stream>>>(dst, deg);
    scan_kernel<<<1, 1024, 0, stream>>>(deg, row_off);
    scatter_kernel<<<(N_EDGES + 255) / 256, 256, 0, stream>>>(src, dst, el, er,
                                                              row_off, cursor, csr_src, w_srt);
    aggregate_kernel<<<N_NODES, 128, 0, stream>>>(ft, csr_src, w_srt, row_off, bias, out);
}

// Round 3
// 314.444 us; speedup vs baseline: 1.3310x; 1.3310x over previous
//
#include <hip/hip_runtime.h>
#include <hip/hip_bf16.h>
#include <math.h>

#define N_NODES 50000
#define N_EDGES 800000
#define IN_F 256
#define HD 128   // H*D
#define NHEAD 4
#define NB_SCAN 196   // ceil(50000/256)

typedef __attribute__((ext_vector_type(8))) short bf16x8;
typedef __attribute__((ext_vector_type(4))) float f32x4;

__device__ __forceinline__ float lrelu(float x){ return x > 0.f ? x : 0.2f * x; }

__device__ __forceinline__ unsigned short f32_to_bf16_rn(float x){
    union { float f; unsigned int u; } v; v.f = x;
    unsigned int r = v.u + 0x7FFFu + ((v.u >> 16) & 1u);
    return (unsigned short)(r >> 16);
}
__device__ __forceinline__ float bf16_to_f32(unsigned short h){
    union { unsigned int u; float f; } v; v.u = ((unsigned int)h) << 16;
    return v.f;
}

__global__ void zero_ints(int* __restrict__ p, int n){
    int i = blockIdx.x * blockDim.x + threadIdx.x;
    if (i < n) p[i] = 0;
}

// ---------------- W pre-transpose + bf16 hi/lo split: Wt[n][k] ----------------
__global__ __launch_bounds__(256) void wsplit_kernel(const float* __restrict__ W,
                                                     unsigned short* __restrict__ Wt_hi,
                                                     unsigned short* __restrict__ Wt_lo){
    int gid = blockIdx.x * 256 + threadIdx.x;   // 128*256 = 32768 total
    int n = gid >> 8;           // 0..127
    int k = gid & 255;          // 0..255
    float x = W[(size_t)k * HD + n];
    unsigned short h = f32_to_bf16_rn(x);
    float r = x - bf16_to_f32(h);
    unsigned short l = f32_to_bf16_rn(r);
    Wt_hi[gid] = h;
    Wt_lo[gid] = l;
}

// ---------------- GEMM: ft[N,128] = feat[N,256] @ W[256,128] via bf16 MFMA split ----------------
// block: 256 thr (4 waves); BM=128 rows; full N=128; K chunks of 64.
__global__ __launch_bounds__(256) void gemm_kernel(const float* __restrict__ feat,
                                                   const unsigned short* __restrict__ Wt_hi,
                                                   const unsigned short* __restrict__ Wt_lo,
                                                   float* __restrict__ ft){
    __shared__ unsigned short Ah[128][72];
    __shared__ unsigned short Al[128][72];
    __shared__ unsigned short Bh[128][72];
    __shared__ unsigned short Bl[128][72];

    const int tid  = threadIdx.x;
    const int lane = tid & 63;
    const int wave = tid >> 6;          // 0..3
    const int wrow = wave * 32;
    const int lrow = lane & 15;
    const int lkh  = (lane >> 4) * 8;   // k sub-offset within 32
    const int row0 = blockIdx.x * 128;

    f32x4 acc[2][8];
#pragma unroll
    for (int i = 0; i < 2; i++)
#pragma unroll
        for (int j = 0; j < 8; j++) acc[i][j] = (f32x4){0.f, 0.f, 0.f, 0.f};

    const int srow = tid >> 1;          // 0..127
    const int skh  = (tid & 1) * 32;    // 0 or 32

    for (int kc = 0; kc < 4; ++kc){
        const int k0 = kc * 64;
        // ---- stage A (f32 -> bf16 hi/lo) ----
        {
            int gr = row0 + srow;
            const float* fp = feat + (size_t)gr * IN_F + k0 + skh;
            unsigned short* ah = &Ah[srow][skh];
            unsigned short* al = &Al[srow][skh];
#pragma unroll
            for (int u = 0; u < 8; ++u){
                float4 v = make_float4(0.f,0.f,0.f,0.f);
                if (gr < N_NODES) v = *(const float4*)(fp + 4 * u);
                ushort4 h, l;
                h.x = f32_to_bf16_rn(v.x); l.x = f32_to_bf16_rn(v.x - bf16_to_f32(h.x));
                h.y = f32_to_bf16_rn(v.y); l.y = f32_to_bf16_rn(v.y - bf16_to_f32(h.y));
                h.z = f32_to_bf16_rn(v.z); l.z = f32_to_bf16_rn(v.z - bf16_to_f32(h.z));
                h.w = f32_to_bf16_rn(v.w); l.w = f32_to_bf16_rn(v.w - bf16_to_f32(h.w));
                *(ushort4*)(ah + 4 * u) = h;
                *(ushort4*)(al + 4 * u) = l;
            }
        }
        // ---- stage B (precomputed bf16 hi/lo, Wt[n][k]) ----
        {
            const unsigned short* bh = Wt_hi + srow * 256 + k0 + skh;
            const unsigned short* bl = Wt_lo + srow * 256 + k0 + skh;
#pragma unroll
            for (int u = 0; u < 4; ++u){
                *(uint4*)(&Bh[srow][skh + 8 * u]) = *(const uint4*)(bh + 8 * u);
                *(uint4*)(&Bl[srow][skh + 8 * u]) = *(const uint4*)(bl + 8 * u);
            }
        }
        __syncthreads();
        // ---- compute ----
#pragma unroll
        for (int kk = 0; kk < 2; ++kk){
            const int kb = kk * 32 + lkh;
            bf16x8 ah0 = *(const bf16x8*)(&Ah[wrow + lrow][kb]);
            bf16x8 ah1 = *(const bf16x8*)(&Ah[wrow + 16 + lrow][kb]);
            bf16x8 al0 = *(const bf16x8*)(&Al[wrow + lrow][kb]);
            bf16x8 al1 = *(const bf16x8*)(&Al[wrow + 16 + lrow][kb]);
#pragma unroll
            for (int nf = 0; nf < 8; ++nf){
                bf16x8 bh = *(const bf16x8*)(&Bh[nf * 16 + lrow][kb]);
                bf16x8 bl = *(const bf16x8*)(&Bl[nf * 16 + lrow][kb]);
                acc[0][nf] = __builtin_amdgcn_mfma_f32_16x16x32_bf16(ah0, bh, acc[0][nf], 0, 0, 0);
                acc[1][nf] = __builtin_amdgcn_mfma_f32_16x16x32_bf16(ah1, bh, acc[1][nf], 0, 0, 0);
                acc[0][nf] = __builtin_amdgcn_mfma_f32_16x16x32_bf16(ah0, bl, acc[0][nf], 0, 0, 0);
                acc[1][nf] = __builtin_amdgcn_mfma_f32_16x16x32_bf16(ah1, bl, acc[1][nf], 0, 0, 0);
                acc[0][nf] = __builtin_amdgcn_mfma_f32_16x16x32_bf16(al0, bh, acc[0][nf], 0, 0, 0);
                acc[1][nf] = __builtin_amdgcn_mfma_f32_16x16x32_bf16(al1, bh, acc[1][nf], 0, 0, 0);
            }
        }
        __syncthreads();
    }
    // ---- epilogue: C/D layout col=lane&15, row=(lane>>4)*4+reg ----
#pragma unroll
    for (int mf = 0; mf < 2; ++mf){
        int rbase = row0 + wrow + mf * 16 + (lane >> 4) * 4;
#pragma unroll
        for (int r = 0; r < 4; ++r){
            int gr = rbase + r;
            if (gr < N_NODES){
                float* op = ft + (size_t)gr * HD + lrow;
#pragma unroll
                for (int nf = 0; nf < 8; ++nf) op[nf * 16] = acc[mf][nf][r];
            }
        }
    }
}

// ---------------- per-node attention logits el/er [N,4] ----------------
__global__ __launch_bounds__(128) void attn_kernel(const float* __restrict__ ft,
                                                   const float* __restrict__ attn_l,
                                                   const float* __restrict__ attn_r,
                                                   float* __restrict__ el,
                                                   float* __restrict__ er){
    int n = blockIdx.x;
    int tid = threadIdx.x;          // 0..127, h = tid>>5, d = tid&31
    float v  = ft[(size_t)n * HD + tid];
    float pl = v * attn_l[tid];
    float pr = v * attn_r[tid];
#pragma unroll
    for (int m = 16; m >= 1; m >>= 1){
        pl += __shfl_xor(pl, m, 64);
        pr += __shfl_xor(pr, m, 64);
    }
    if ((tid & 31) == 0){
        el[n * NHEAD + (tid >> 5)] = pl;
        er[n * NHEAD + (tid >> 5)] = pr;
    }
}

// ---------------- CSR build ----------------
__global__ void degree_kernel(const int* __restrict__ dst, int* __restrict__ deg){
    int e = blockIdx.x * blockDim.x + threadIdx.x;
    if (e < N_EDGES) atomicAdd(&deg[dst[e]], 1);
}

// hierarchical scan: part -> mid -> add
__global__ __launch_bounds__(256) void scan_part(const int* __restrict__ deg,
                                                 int* __restrict__ row_off,
                                                 int* __restrict__ blk_sums){
    __shared__ int lds[256];
    int tid = threadIdx.x;
    int i = blockIdx.x * 256 + tid;
    int v = (i < N_NODES) ? deg[i] : 0;
    int x = v;
    lds[tid] = x;
    __syncthreads();
    for (int off = 1; off < 256; off <<= 1){
        int t = (tid >= off) ? lds[tid - off] : 0;
        __syncthreads();
        x += t;
        lds[tid] = x;
        __syncthreads();
    }
    if (i < N_NODES) row_off[i] = x - v;          // local exclusive
    if (tid == 255) blk_sums[blockIdx.x] = x;     // block total
}

__global__ __launch_bounds__(256) void scan_mid(int* __restrict__ blk_sums,
                                                int* __restrict__ blk_off){
    __shared__ int lds[256];
    int tid = threadIdx.x;
    int v = (tid < NB_SCAN) ? blk_sums[tid] : 0;
    int x = v;
    lds[tid] = x;
    __syncthreads();
    for (int off = 1; off < 256; off <<= 1){
        int t = (tid >= off) ? lds[tid - off] : 0;
        __syncthreads();
        x += t;
        lds[tid] = x;
        __syncthreads();
    }
    blk_off[tid] = x - v;                          // exclusive
}

__global__ __launch_bounds__(256) void scan_add(int* __restrict__ row_off,
                                                const int* __restrict__ blk_off){
    int i = blockIdx.x * 256 + threadIdx.x;
    if (i < N_NODES) row_off[i] += blk_off[blockIdx.x];
    if (blockIdx.x == 0 && threadIdx.x == 0) row_off[N_NODES] = N_EDGES;
}

__global__ void scatter_kernel(const int* __restrict__ src, const int* __restrict__ dst,
                               const float* __restrict__ el, const float* __restrict__ er,
                               const int* __restrict__ row_off, int* __restrict__ cursor,
                               int* __restrict__ csr_src, float* __restrict__ w_srt){
    int e = blockIdx.x * blockDim.x + threadIdx.x;
    if (e >= N_EDGES) return;
    int d = dst[e], s = src[e];
    int pos = row_off[d] + atomicAdd(&cursor[d], 1);
    csr_src[pos] = s;
    float4 elv = *(const float4*)(el + (size_t)s * NHEAD);
    float4 erv = *(const float4*)(er + (size_t)d * NHEAD);
    float4 w;
    w.x = __expf(lrelu(elv.x + erv.x));
    w.y = __expf(lrelu(elv.y + erv.y));
    w.z = __expf(lrelu(elv.z + erv.z));
    w.w = __expf(lrelu(elv.w + erv.w));
    *(float4*)(w_srt + (size_t)pos * NHEAD) = w;
}

// ---------------- aggregation: one block per dst node ----------------
__global__ __launch_bounds__(128) void aggregate_kernel(const float* __restrict__ ft,
                                                        const int* __restrict__ csr_src,
                                                        const float* __restrict__ w_srt,
                                                        const int* __restrict__ row_off,
                                                        const float* __restrict__ bias,
                                                        float* __restrict__ out){
    int n   = blockIdx.x;
    int tid = threadIdx.x;      // 0..127 : h = tid>>5
    int h   = tid >> 5;
    int beg = row_off[n], end = row_off[n + 1];
    float acc = 0.f, sacc = 0.f;
    for (int i = beg; i < end; ++i){
        int s   = csr_src[i];
        float w = w_srt[(size_t)i * NHEAD + h];
        acc  += w * ft[(size_t)s * HD + tid];
        sacc += w;
    }
    float o = (end > beg) ? (acc / sacc) : 0.f;
    out[(size_t)n * HD + tid] = o + bias[tid];
}

extern "C" void kernel_launch(void* const* d_in, const int* in_sizes, int n_in,
                              void* d_out, int out_size, void* d_ws, size_t ws_size,
                              hipStream_t stream){
    const float* feat   = (const float*)d_in[0];
    const int*   src    = (const int*)  d_in[1];
    const int*   dst    = (const int*)  d_in[2];
    const float* W      = (const float*)d_in[3];
    const float* attn_l = (const float*)d_in[4];
    const float* attn_r = (const float*)d_in[5];
    const float* bias   = (const float*)d_in[6];
    float* out = (float*)d_out;
    char*  ws  = (char*)d_ws;

    // workspace layout (bytes)
    float* ft      = (float*)(ws + 0);          // 50000*128*4 = 25,600,000
    float* el      = (float*)(ws + 25600000);   // 800,000
    float* er      = (float*)(ws + 26400000);   // 800,000
    int*   deg     = (int*)  (ws + 27200000);   // 200,000
    int*   cursor  = (int*)  (ws + 27400000);   // 200,000 (contiguous after deg)
    int*   row_off = (int*)  (ws + 27600000);   // 200,004 (pad to 200,064)
    int*   csr_src = (int*)  (ws + 27800064);   // 3,200,000
    float* w_srt   = (float*)(ws + 31000064);   // 12,800,000

    // transient aliases (used only BEFORE their hosts are written):
    unsigned short* Wt_hi = (unsigned short*)csr_src;          // 65,536 B (gemm-time only)
    unsigned short* Wt_lo = Wt_hi + 32768;                     // 65,536 B
    int* blk_sums = (int*)w_srt;                               // scan-time only
    int* blk_off  = blk_sums + 256;

    zero_ints<<<(2 * N_NODES + 255) / 256, 256, 0, stream>>>(deg, 2 * N_NODES);
    wsplit_kernel<<<128, 256, 0, stream>>>(W, Wt_hi, Wt_lo);
    gemm_kernel<<<(N_NODES + 127) / 128, 256, 0, stream>>>(feat, Wt_hi, Wt_lo, ft);
    attn_kernel<<<N_NODES, 128, 0, stream>>>(ft, attn_l, attn_r, el, er);
    degree_kernel<<<(N_EDGES + 255) / 256, 256, 0, stream>>>(dst, deg);
    scan_part<<<NB_SCAN, 256, 0, stream>>>(deg, row_off, blk_sums);
    scan_mid<<<1, 256, 0, stream>>>(blk_sums, blk_off);
    scan_add<<<NB_SCAN, 256, 0, stream>>>(row_off, blk_off);
    scatter_kernel<<<(N_EDGES + 255) / 256, 256, 0, stream>>>(src, dst, el, er,
                                                              row_off, cursor, csr_src, w_srt);
    aggregate_kernel<<<N_NODES, 128, 0, stream>>>(ft, csr_src, w_srt, row_off, bias, out);
}

// Round 4
// 253.551 us; speedup vs baseline: 1.6507x; 1.2402x over previous
//
#include <hip/hip_runtime.h>
#include <hip/hip_bf16.h>
#include <math.h>

#define N_NODES 50000
#define N_EDGES 800000
#define IN_F 256
#define HD 128   // H*D
#define NHEAD 4
#define NB_SCAN 196   // ceil(50000/256)

typedef __attribute__((ext_vector_type(8))) short bf16x8;
typedef __attribute__((ext_vector_type(4))) float f32x4;

__device__ __forceinline__ float lrelu(float x){ return x > 0.f ? x : 0.2f * x; }

__device__ __forceinline__ unsigned short f32_to_bf16_rn(float x){
    union { float f; unsigned int u; } v; v.f = x;
    unsigned int r = v.u + 0x7FFFu + ((v.u >> 16) & 1u);
    return (unsigned short)(r >> 16);
}
__device__ __forceinline__ float bf16_to_f32(unsigned short h){
    union { unsigned int u; float f; } v; v.u = ((unsigned int)h) << 16;
    return v.f;
}
__device__ __forceinline__ float bflo(unsigned int u){
    union { unsigned int x; float f; } v; v.x = u << 16; return v.f;
}
__device__ __forceinline__ float bfhi(unsigned int u){
    union { unsigned int x; float f; } v; v.x = u & 0xFFFF0000u; return v.f;
}

__global__ void zero_ints(int* __restrict__ p, int n){
    int i = blockIdx.x * blockDim.x + threadIdx.x;
    if (i < n) p[i] = 0;
}

// ---------------- W pre-transpose + bf16 hi/lo split: Wt[n][k] ----------------
__global__ __launch_bounds__(256) void wsplit_kernel(const float* __restrict__ W,
                                                     unsigned short* __restrict__ Wt_hi,
                                                     unsigned short* __restrict__ Wt_lo){
    int gid = blockIdx.x * 256 + threadIdx.x;   // 128*256 = 32768 total
    int n = gid >> 8;           // 0..127
    int k = gid & 255;          // 0..255
    float x = W[(size_t)k * HD + n];
    unsigned short h = f32_to_bf16_rn(x);
    float r = x - bf16_to_f32(h);
    unsigned short l = f32_to_bf16_rn(r);
    Wt_hi[gid] = h;
    Wt_lo[gid] = l;
}

// ---------------- GEMM: ftb[N,128](bf16) = feat[N,256] @ W[256,128], fused el/er ----------------
// block: 256 thr (4 waves); BM=128 rows; full N=128; K chunks of 64.
__global__ __launch_bounds__(256) void gemm_kernel(const float* __restrict__ feat,
                                                   const unsigned short* __restrict__ Wt_hi,
                                                   const unsigned short* __restrict__ Wt_lo,
                                                   const float* __restrict__ attn_l,
                                                   const float* __restrict__ attn_r,
                                                   unsigned short* __restrict__ ftb,
                                                   float* __restrict__ el,
                                                   float* __restrict__ er){
    __shared__ unsigned short Ah[128][72];
    __shared__ unsigned short Al[128][72];
    __shared__ unsigned short Bh[128][72];
    __shared__ unsigned short Bl[128][72];

    const int tid  = threadIdx.x;
    const int lane = tid & 63;
    const int wave = tid >> 6;          // 0..3
    const int wrow = wave * 32;
    const int lrow = lane & 15;
    const int lkh  = (lane >> 4) * 8;   // k sub-offset within 32
    const int row0 = blockIdx.x * 128;

    f32x4 acc[2][8];
#pragma unroll
    for (int i = 0; i < 2; i++)
#pragma unroll
        for (int j = 0; j < 8; j++) acc[i][j] = (f32x4){0.f, 0.f, 0.f, 0.f};

    const int srow = tid >> 1;          // 0..127
    const int skh  = (tid & 1) * 32;    // 0 or 32

    for (int kc = 0; kc < 4; ++kc){
        const int k0 = kc * 64;
        // ---- stage A (f32 -> bf16 hi/lo) ----
        {
            int gr = row0 + srow;
            const float* fp = feat + (size_t)gr * IN_F + k0 + skh;
            unsigned short* ah = &Ah[srow][skh];
            unsigned short* al = &Al[srow][skh];
#pragma unroll
            for (int u = 0; u < 8; ++u){
                float4 v = make_float4(0.f,0.f,0.f,0.f);
                if (gr < N_NODES) v = *(const float4*)(fp + 4 * u);
                ushort4 h, l;
                h.x = f32_to_bf16_rn(v.x); l.x = f32_to_bf16_rn(v.x - bf16_to_f32(h.x));
                h.y = f32_to_bf16_rn(v.y); l.y = f32_to_bf16_rn(v.y - bf16_to_f32(h.y));
                h.z = f32_to_bf16_rn(v.z); l.z = f32_to_bf16_rn(v.z - bf16_to_f32(h.z));
                h.w = f32_to_bf16_rn(v.w); l.w = f32_to_bf16_rn(v.w - bf16_to_f32(h.w));
                *(ushort4*)(ah + 4 * u) = h;
                *(ushort4*)(al + 4 * u) = l;
            }
        }
        // ---- stage B (precomputed bf16 hi/lo, Wt[n][k]) ----
        {
            const unsigned short* bh = Wt_hi + srow * 256 + k0 + skh;
            const unsigned short* bl = Wt_lo + srow * 256 + k0 + skh;
#pragma unroll
            for (int u = 0; u < 4; ++u){
                *(uint4*)(&Bh[srow][skh + 8 * u]) = *(const uint4*)(bh + 8 * u);
                *(uint4*)(&Bl[srow][skh + 8 * u]) = *(const uint4*)(bl + 8 * u);
            }
        }
        __syncthreads();
        // ---- compute ----
#pragma unroll
        for (int kk = 0; kk < 2; ++kk){
            const int kb = kk * 32 + lkh;
            bf16x8 ah0 = *(const bf16x8*)(&Ah[wrow + lrow][kb]);
            bf16x8 ah1 = *(const bf16x8*)(&Ah[wrow + 16 + lrow][kb]);
            bf16x8 al0 = *(const bf16x8*)(&Al[wrow + lrow][kb]);
            bf16x8 al1 = *(const bf16x8*)(&Al[wrow + 16 + lrow][kb]);
#pragma unroll
            for (int nf = 0; nf < 8; ++nf){
                bf16x8 bh = *(const bf16x8*)(&Bh[nf * 16 + lrow][kb]);
                bf16x8 bl = *(const bf16x8*)(&Bl[nf * 16 + lrow][kb]);
                acc[0][nf] = __builtin_amdgcn_mfma_f32_16x16x32_bf16(ah0, bh, acc[0][nf], 0, 0, 0);
                acc[1][nf] = __builtin_amdgcn_mfma_f32_16x16x32_bf16(ah1, bh, acc[1][nf], 0, 0, 0);
                acc[0][nf] = __builtin_amdgcn_mfma_f32_16x16x32_bf16(ah0, bl, acc[0][nf], 0, 0, 0);
                acc[1][nf] = __builtin_amdgcn_mfma_f32_16x16x32_bf16(ah1, bl, acc[1][nf], 0, 0, 0);
                acc[0][nf] = __builtin_amdgcn_mfma_f32_16x16x32_bf16(al0, bh, acc[0][nf], 0, 0, 0);
                acc[1][nf] = __builtin_amdgcn_mfma_f32_16x16x32_bf16(al1, bh, acc[1][nf], 0, 0, 0);
            }
        }
        __syncthreads();
    }
    // ---- epilogue: C/D layout col=lrow+nf*16, row=wrow+mf*16+(lane>>4)*4+r ----
    float alv[8], arv[8];
#pragma unroll
    for (int nf = 0; nf < 8; ++nf){
        alv[nf] = attn_l[lrow + nf * 16];
        arv[nf] = attn_r[lrow + nf * 16];
    }
#pragma unroll
    for (int mf = 0; mf < 2; ++mf){
#pragma unroll
        for (int r = 0; r < 4; ++r){
            int gr = row0 + wrow + mf * 16 + (lane >> 4) * 4 + r;
            // bf16 ft store
            if (gr < N_NODES){
                unsigned short* op = ftb + (size_t)gr * HD + lrow;
#pragma unroll
                for (int nf = 0; nf < 8; ++nf) op[nf * 16] = f32_to_bf16_rn(acc[mf][nf][r]);
            }
            // per-head partial dots: head h owns cols {lrow+2h*16, lrow+(2h+1)*16}
            float pl0 = acc[mf][0][r] * alv[0] + acc[mf][1][r] * alv[1];
            float pl1 = acc[mf][2][r] * alv[2] + acc[mf][3][r] * alv[3];
            float pl2 = acc[mf][4][r] * alv[4] + acc[mf][5][r] * alv[5];
            float pl3 = acc[mf][6][r] * alv[6] + acc[mf][7][r] * alv[7];
            float pr0 = acc[mf][0][r] * arv[0] + acc[mf][1][r] * arv[1];
            float pr1 = acc[mf][2][r] * arv[2] + acc[mf][3][r] * arv[3];
            float pr2 = acc[mf][4][r] * arv[4] + acc[mf][5][r] * arv[5];
            float pr3 = acc[mf][6][r] * arv[6] + acc[mf][7][r] * arv[7];
#pragma unroll
            for (int m = 1; m <= 8; m <<= 1){
                pl0 += __shfl_xor(pl0, m, 64); pl1 += __shfl_xor(pl1, m, 64);
                pl2 += __shfl_xor(pl2, m, 64); pl3 += __shfl_xor(pl3, m, 64);
                pr0 += __shfl_xor(pr0, m, 64); pr1 += __shfl_xor(pr1, m, 64);
                pr2 += __shfl_xor(pr2, m, 64); pr3 += __shfl_xor(pr3, m, 64);
            }
            if ((lane & 15) == 0 && gr < N_NODES){
                *(float4*)(el + (size_t)gr * NHEAD) = make_float4(pl0, pl1, pl2, pl3);
                *(float4*)(er + (size_t)gr * NHEAD) = make_float4(pr0, pr1, pr2, pr3);
            }
        }
    }
}

// ---------------- CSR build ----------------
__global__ void degree_kernel(const int* __restrict__ dst, int* __restrict__ deg){
    int e = blockIdx.x * blockDim.x + threadIdx.x;
    if (e < N_EDGES) atomicAdd(&deg[dst[e]], 1);
}

// hierarchical scan: part -> mid -> add
__global__ __launch_bounds__(256) void scan_part(const int* __restrict__ deg,
                                                 int* __restrict__ row_off,
                                                 int* __restrict__ blk_sums){
    __shared__ int lds[256];
    int tid = threadIdx.x;
    int i = blockIdx.x * 256 + tid;
    int v = (i < N_NODES) ? deg[i] : 0;
    int x = v;
    lds[tid] = x;
    __syncthreads();
    for (int off = 1; off < 256; off <<= 1){
        int t = (tid >= off) ? lds[tid - off] : 0;
        __syncthreads();
        x += t;
        lds[tid] = x;
        __syncthreads();
    }
    if (i < N_NODES) row_off[i] = x - v;          // local exclusive
    if (tid == 255) blk_sums[blockIdx.x] = x;     // block total
}

__global__ __launch_bounds__(256) void scan_mid(int* __restrict__ blk_sums,
                                                int* __restrict__ blk_off){
    __shared__ int lds[256];
    int tid = threadIdx.x;
    int v = (tid < NB_SCAN) ? blk_sums[tid] : 0;
    int x = v;
    lds[tid] = x;
    __syncthreads();
    for (int off = 1; off < 256; off <<= 1){
        int t = (tid >= off) ? lds[tid - off] : 0;
        __syncthreads();
        x += t;
        lds[tid] = x;
        __syncthreads();
    }
    blk_off[tid] = x - v;                          // exclusive
}

__global__ __launch_bounds__(256) void scan_add(int* __restrict__ row_off,
                                                const int* __restrict__ blk_off){
    int i = blockIdx.x * 256 + threadIdx.x;
    if (i < N_NODES) row_off[i] += blk_off[blockIdx.x];
    if (blockIdx.x == 0 && threadIdx.x == 0) row_off[N_NODES] = N_EDGES;
}

__global__ void scatter_kernel(const int* __restrict__ src, const int* __restrict__ dst,
                               const float* __restrict__ el, const float* __restrict__ er,
                               const int* __restrict__ row_off, int* __restrict__ cursor,
                               int* __restrict__ csr_src, float* __restrict__ w_srt){
    int e = blockIdx.x * blockDim.x + threadIdx.x;
    if (e >= N_EDGES) return;
    int d = dst[e], s = src[e];
    int pos = row_off[d] + atomicAdd(&cursor[d], 1);
    csr_src[pos] = s;
    float4 elv = *(const float4*)(el + (size_t)s * NHEAD);
    float4 erv = *(const float4*)(er + (size_t)d * NHEAD);
    float4 w;
    w.x = __expf(lrelu(elv.x + erv.x));
    w.y = __expf(lrelu(elv.y + erv.y));
    w.z = __expf(lrelu(elv.z + erv.z));
    w.w = __expf(lrelu(elv.w + erv.w));
    *(float4*)(w_srt + (size_t)pos * NHEAD) = w;
}

// ---------------- aggregation: 4 nodes/block, one wave per node, 2 cols per lane ----------------
__global__ __launch_bounds__(256) void aggregate_kernel(const unsigned short* __restrict__ ftb,
                                                        const int* __restrict__ csr_src,
                                                        const float* __restrict__ w_srt,
                                                        const int* __restrict__ row_off,
                                                        const float* __restrict__ bias,
                                                        float* __restrict__ out){
    int n    = blockIdx.x * 4 + (threadIdx.x >> 6);
    int lane = threadIdx.x & 63;        // cols 2*lane, 2*lane+1
    int h    = lane >> 4;               // head = (2*lane)/32
    int beg  = row_off[n], end = row_off[n + 1];

    float a0 = 0.f, a1 = 0.f, ws = 0.f;
    int i = beg;
    for (; i + 4 <= end; i += 4){
        int s0 = csr_src[i + 0], s1 = csr_src[i + 1], s2 = csr_src[i + 2], s3 = csr_src[i + 3];
        float w0 = w_srt[(size_t)(i + 0) * NHEAD + h];
        float w1 = w_srt[(size_t)(i + 1) * NHEAD + h];
        float w2 = w_srt[(size_t)(i + 2) * NHEAD + h];
        float w3 = w_srt[(size_t)(i + 3) * NHEAD + h];
        unsigned int f0 = *(const unsigned int*)(ftb + (size_t)s0 * HD + 2 * lane);
        unsigned int f1 = *(const unsigned int*)(ftb + (size_t)s1 * HD + 2 * lane);
        unsigned int f2 = *(const unsigned int*)(ftb + (size_t)s2 * HD + 2 * lane);
        unsigned int f3 = *(const unsigned int*)(ftb + (size_t)s3 * HD + 2 * lane);
        a0 += w0 * bflo(f0) + w1 * bflo(f1) + w2 * bflo(f2) + w3 * bflo(f3);
        a1 += w0 * bfhi(f0) + w1 * bfhi(f1) + w2 * bfhi(f2) + w3 * bfhi(f3);
        ws += (w0 + w1) + (w2 + w3);
    }
    for (; i < end; ++i){
        int s = csr_src[i];
        float w = w_srt[(size_t)i * NHEAD + h];
        unsigned int f = *(const unsigned int*)(ftb + (size_t)s * HD + 2 * lane);
        a0 += w * bflo(f);
        a1 += w * bfhi(f);
        ws += w;
    }
    float inv = (end > beg) ? 1.f / ws : 0.f;
    float2 o;
    o.x = a0 * inv + bias[2 * lane + 0];
    o.y = a1 * inv + bias[2 * lane + 1];
    *(float2*)(out + (size_t)n * HD + 2 * lane) = o;
}

extern "C" void kernel_launch(void* const* d_in, const int* in_sizes, int n_in,
                              void* d_out, int out_size, void* d_ws, size_t ws_size,
                              hipStream_t stream){
    const float* feat   = (const float*)d_in[0];
    const int*   src    = (const int*)  d_in[1];
    const int*   dst    = (const int*)  d_in[2];
    const float* W      = (const float*)d_in[3];
    const float* attn_l = (const float*)d_in[4];
    const float* attn_r = (const float*)d_in[5];
    const float* bias   = (const float*)d_in[6];
    float* out = (float*)d_out;
    char*  ws  = (char*)d_ws;

    // workspace layout (bytes)
    unsigned short* ftb = (unsigned short*)(ws + 0);   // 50000*128*2 = 12,800,000
    float* el      = (float*)(ws + 12800000);   // 800,000
    float* er      = (float*)(ws + 13600000);   // 800,000
    int*   deg     = (int*)  (ws + 14400000);   // 200,000
    int*   cursor  = (int*)  (ws + 14600000);   // 200,000 (contiguous after deg)
    int*   row_off = (int*)  (ws + 14800000);   // 200,004 (pad to 200,064)
    int*   csr_src = (int*)  (ws + 15000064);   // 3,200,000
    float* w_srt   = (float*)(ws + 18200064);   // 12,800,000  (total ~31 MB)

    // transient aliases (used only BEFORE their hosts are written):
    unsigned short* Wt_hi = (unsigned short*)csr_src;          // 65,536 B (gemm-time only)
    unsigned short* Wt_lo = Wt_hi + 32768;                     // 65,536 B
    int* blk_sums = (int*)w_srt;                               // scan-time only
    int* blk_off  = blk_sums + 256;

    zero_ints<<<(2 * N_NODES + 255) / 256, 256, 0, stream>>>(deg, 2 * N_NODES);
    wsplit_kernel<<<128, 256, 0, stream>>>(W, Wt_hi, Wt_lo);
    gemm_kernel<<<(N_NODES + 127) / 128, 256, 0, stream>>>(feat, Wt_hi, Wt_lo,
                                                           attn_l, attn_r, ftb, el, er);
    degree_kernel<<<(N_EDGES + 255) / 256, 256, 0, stream>>>(dst, deg);
    scan_part<<<NB_SCAN, 256, 0, stream>>>(deg, row_off, blk_sums);
    scan_mid<<<1, 256, 0, stream>>>(blk_sums, blk_off);
    scan_add<<<NB_SCAN, 256, 0, stream>>>(row_off, blk_off);
    scatter_kernel<<<(N_EDGES + 255) / 256, 256, 0, stream>>>(src, dst, el, er,
                                                              row_off, cursor, csr_src, w_srt);
    aggregate_kernel<<<(N_NODES + 3) / 4, 256, 0, stream>>>(ftb, csr_src, w_srt,
                                                            row_off, bias, out);
}

// Round 5
// 248.046 us; speedup vs baseline: 1.6873x; 1.0222x over previous
//
#include <hip/hip_runtime.h>
#include <hip/hip_bf16.h>
#include <math.h>

#define N_NODES 50000
#define N_EDGES 800000
#define IN_F 256
#define HD 128   // H*D
#define NHEAD 4
#define NB_SCAN 196   // ceil(50000/256)

typedef __attribute__((ext_vector_type(8))) short bf16x8;
typedef __attribute__((ext_vector_type(4))) float f32x4;

__device__ __forceinline__ float lrelu(float x){ return x > 0.f ? x : 0.2f * x; }

__device__ __forceinline__ unsigned short f32_to_bf16_rn(float x){
    union { float f; unsigned int u; } v; v.f = x;
    unsigned int r = v.u + 0x7FFFu + ((v.u >> 16) & 1u);
    return (unsigned short)(r >> 16);
}
__device__ __forceinline__ float bf16_to_f32(unsigned short h){
    union { unsigned int u; float f; } v; v.u = ((unsigned int)h) << 16;
    return v.f;
}
__device__ __forceinline__ float bflo(unsigned int u){
    union { unsigned int x; float f; } v; v.x = u << 16; return v.f;
}
__device__ __forceinline__ float bfhi(unsigned int u){
    union { unsigned int x; float f; } v; v.x = u & 0xFFFF0000u; return v.f;
}

__global__ void zero_ints(int* __restrict__ p, int n){
    int i = blockIdx.x * blockDim.x + threadIdx.x;
    if (i < n) p[i] = 0;
}

// ---------------- W pre-transpose + bf16 hi/lo split: Wt[n][k] ----------------
__global__ __launch_bounds__(256) void wsplit_kernel(const float* __restrict__ W,
                                                     unsigned short* __restrict__ Wt_hi,
                                                     unsigned short* __restrict__ Wt_lo){
    int gid = blockIdx.x * 256 + threadIdx.x;   // 128*256 = 32768 total
    int n = gid >> 8;           // 0..127
    int k = gid & 255;          // 0..255
    float x = W[(size_t)k * HD + n];
    unsigned short h = f32_to_bf16_rn(x);
    float r = x - bf16_to_f32(h);
    unsigned short l = f32_to_bf16_rn(r);
    Wt_hi[gid] = h;
    Wt_lo[gid] = l;
}

// ---------------- GEMM: ftb[N,128](bf16) = feat[N,256] @ W[256,128], fused el/er ----------------
__global__ __launch_bounds__(256) void gemm_kernel(const float* __restrict__ feat,
                                                   const unsigned short* __restrict__ Wt_hi,
                                                   const unsigned short* __restrict__ Wt_lo,
                                                   const float* __restrict__ attn_l,
                                                   const float* __restrict__ attn_r,
                                                   unsigned short* __restrict__ ftb,
                                                   float* __restrict__ el,
                                                   float* __restrict__ er){
    __shared__ unsigned short Ah[128][72];
    __shared__ unsigned short Al[128][72];
    __shared__ unsigned short Bh[128][72];
    __shared__ unsigned short Bl[128][72];

    const int tid  = threadIdx.x;
    const int lane = tid & 63;
    const int wave = tid >> 6;          // 0..3
    const int wrow = wave * 32;
    const int lrow = lane & 15;
    const int lkh  = (lane >> 4) * 8;   // k sub-offset within 32
    const int row0 = blockIdx.x * 128;

    f32x4 acc[2][8];
#pragma unroll
    for (int i = 0; i < 2; i++)
#pragma unroll
        for (int j = 0; j < 8; j++) acc[i][j] = (f32x4){0.f, 0.f, 0.f, 0.f};

    const int srow = tid >> 1;          // 0..127
    const int skh  = (tid & 1) * 32;    // 0 or 32

    for (int kc = 0; kc < 4; ++kc){
        const int k0 = kc * 64;
        // ---- stage A (f32 -> bf16 hi/lo) ----
        {
            int gr = row0 + srow;
            const float* fp = feat + (size_t)gr * IN_F + k0 + skh;
            unsigned short* ah = &Ah[srow][skh];
            unsigned short* al = &Al[srow][skh];
#pragma unroll
            for (int u = 0; u < 8; ++u){
                float4 v = make_float4(0.f,0.f,0.f,0.f);
                if (gr < N_NODES) v = *(const float4*)(fp + 4 * u);
                ushort4 h, l;
                h.x = f32_to_bf16_rn(v.x); l.x = f32_to_bf16_rn(v.x - bf16_to_f32(h.x));
                h.y = f32_to_bf16_rn(v.y); l.y = f32_to_bf16_rn(v.y - bf16_to_f32(h.y));
                h.z = f32_to_bf16_rn(v.z); l.z = f32_to_bf16_rn(v.z - bf16_to_f32(h.z));
                h.w = f32_to_bf16_rn(v.w); l.w = f32_to_bf16_rn(v.w - bf16_to_f32(h.w));
                *(ushort4*)(ah + 4 * u) = h;
                *(ushort4*)(al + 4 * u) = l;
            }
        }
        // ---- stage B (precomputed bf16 hi/lo, Wt[n][k]) ----
        {
            const unsigned short* bh = Wt_hi + srow * 256 + k0 + skh;
            const unsigned short* bl = Wt_lo + srow * 256 + k0 + skh;
#pragma unroll
            for (int u = 0; u < 4; ++u){
                *(uint4*)(&Bh[srow][skh + 8 * u]) = *(const uint4*)(bh + 8 * u);
                *(uint4*)(&Bl[srow][skh + 8 * u]) = *(const uint4*)(bl + 8 * u);
            }
        }
        __syncthreads();
        // ---- compute ----
#pragma unroll
        for (int kk = 0; kk < 2; ++kk){
            const int kb = kk * 32 + lkh;
            bf16x8 ah0 = *(const bf16x8*)(&Ah[wrow + lrow][kb]);
            bf16x8 ah1 = *(const bf16x8*)(&Ah[wrow + 16 + lrow][kb]);
            bf16x8 al0 = *(const bf16x8*)(&Al[wrow + lrow][kb]);
            bf16x8 al1 = *(const bf16x8*)(&Al[wrow + 16 + lrow][kb]);
#pragma unroll
            for (int nf = 0; nf < 8; ++nf){
                bf16x8 bh = *(const bf16x8*)(&Bh[nf * 16 + lrow][kb]);
                bf16x8 bl = *(const bf16x8*)(&Bl[nf * 16 + lrow][kb]);
                acc[0][nf] = __builtin_amdgcn_mfma_f32_16x16x32_bf16(ah0, bh, acc[0][nf], 0, 0, 0);
                acc[1][nf] = __builtin_amdgcn_mfma_f32_16x16x32_bf16(ah1, bh, acc[1][nf], 0, 0, 0);
                acc[0][nf] = __builtin_amdgcn_mfma_f32_16x16x32_bf16(ah0, bl, acc[0][nf], 0, 0, 0);
                acc[1][nf] = __builtin_amdgcn_mfma_f32_16x16x32_bf16(ah1, bl, acc[1][nf], 0, 0, 0);
                acc[0][nf] = __builtin_amdgcn_mfma_f32_16x16x32_bf16(al0, bh, acc[0][nf], 0, 0, 0);
                acc[1][nf] = __builtin_amdgcn_mfma_f32_16x16x32_bf16(al1, bh, acc[1][nf], 0, 0, 0);
            }
        }
        __syncthreads();
    }
    // ---- epilogue: C/D layout col=lrow+nf*16, row=wrow+mf*16+(lane>>4)*4+r ----
    float alv[8], arv[8];
#pragma unroll
    for (int nf = 0; nf < 8; ++nf){
        alv[nf] = attn_l[lrow + nf * 16];
        arv[nf] = attn_r[lrow + nf * 16];
    }
#pragma unroll
    for (int mf = 0; mf < 2; ++mf){
#pragma unroll
        for (int r = 0; r < 4; ++r){
            int gr = row0 + wrow + mf * 16 + (lane >> 4) * 4 + r;
            if (gr < N_NODES){
                unsigned short* op = ftb + (size_t)gr * HD + lrow;
#pragma unroll
                for (int nf = 0; nf < 8; ++nf) op[nf * 16] = f32_to_bf16_rn(acc[mf][nf][r]);
            }
            float pl0 = acc[mf][0][r] * alv[0] + acc[mf][1][r] * alv[1];
            float pl1 = acc[mf][2][r] * alv[2] + acc[mf][3][r] * alv[3];
            float pl2 = acc[mf][4][r] * alv[4] + acc[mf][5][r] * alv[5];
            float pl3 = acc[mf][6][r] * alv[6] + acc[mf][7][r] * alv[7];
            float pr0 = acc[mf][0][r] * arv[0] + acc[mf][1][r] * arv[1];
            float pr1 = acc[mf][2][r] * arv[2] + acc[mf][3][r] * arv[3];
            float pr2 = acc[mf][4][r] * arv[4] + acc[mf][5][r] * arv[5];
            float pr3 = acc[mf][6][r] * arv[6] + acc[mf][7][r] * arv[7];
#pragma unroll
            for (int m = 1; m <= 8; m <<= 1){
                pl0 += __shfl_xor(pl0, m, 64); pl1 += __shfl_xor(pl1, m, 64);
                pl2 += __shfl_xor(pl2, m, 64); pl3 += __shfl_xor(pl3, m, 64);
                pr0 += __shfl_xor(pr0, m, 64); pr1 += __shfl_xor(pr1, m, 64);
                pr2 += __shfl_xor(pr2, m, 64); pr3 += __shfl_xor(pr3, m, 64);
            }
            if ((lane & 15) == 0 && gr < N_NODES){
                *(float4*)(el + (size_t)gr * NHEAD) = make_float4(pl0, pl1, pl2, pl3);
                *(float4*)(er + (size_t)gr * NHEAD) = make_float4(pr0, pr1, pr2, pr3);
            }
        }
    }
}

// ---------------- CSR build: degree + rank in one pass ----------------
__global__ void degree_kernel(const int* __restrict__ dst, int* __restrict__ deg,
                              int* __restrict__ rank){
    int e = blockIdx.x * blockDim.x + threadIdx.x;
    if (e < N_EDGES) rank[e] = atomicAdd(&deg[dst[e]], 1);
}

// hierarchical scan: part -> mid -> add
__global__ __launch_bounds__(256) void scan_part(const int* __restrict__ deg,
                                                 int* __restrict__ row_off,
                                                 int* __restrict__ blk_sums){
    __shared__ int lds[256];
    int tid = threadIdx.x;
    int i = blockIdx.x * 256 + tid;
    int v = (i < N_NODES) ? deg[i] : 0;
    int x = v;
    lds[tid] = x;
    __syncthreads();
    for (int off = 1; off < 256; off <<= 1){
        int t = (tid >= off) ? lds[tid - off] : 0;
        __syncthreads();
        x += t;
        lds[tid] = x;
        __syncthreads();
    }
    if (i < N_NODES) row_off[i] = x - v;          // local exclusive
    if (tid == 255) blk_sums[blockIdx.x] = x;     // block total
}

__global__ __launch_bounds__(256) void scan_mid(int* __restrict__ blk_sums,
                                                int* __restrict__ blk_off){
    __shared__ int lds[256];
    int tid = threadIdx.x;
    int v = (tid < NB_SCAN) ? blk_sums[tid] : 0;
    int x = v;
    lds[tid] = x;
    __syncthreads();
    for (int off = 1; off < 256; off <<= 1){
        int t = (tid >= off) ? lds[tid - off] : 0;
        __syncthreads();
        x += t;
        lds[tid] = x;
        __syncthreads();
    }
    blk_off[tid] = x - v;                          // exclusive
}

__global__ __launch_bounds__(256) void scan_add(int* __restrict__ row_off,
                                                const int* __restrict__ blk_off){
    int i = blockIdx.x * 256 + threadIdx.x;
    if (i < N_NODES) row_off[i] += blk_off[blockIdx.x];
    if (blockIdx.x == 0 && threadIdx.x == 0) row_off[N_NODES] = N_EDGES;
}

// ---------------- scatter: atomic-free, 4B per edge ----------------
__global__ void scatter_kernel(const int* __restrict__ src, const int* __restrict__ dst,
                               const int* __restrict__ rank, const int* __restrict__ row_off,
                               int* __restrict__ csr_src){
    int e = blockIdx.x * blockDim.x + threadIdx.x;
    if (e >= N_EDGES) return;
    csr_src[row_off[dst[e]] + rank[e]] = src[e];
}

// ---------------- aggregation: 4 nodes/block, one wave per node, on-the-fly weights ----------------
__global__ __launch_bounds__(256) void aggregate_kernel(const unsigned short* __restrict__ ftb,
                                                        const int* __restrict__ csr_src,
                                                        const float* __restrict__ el,
                                                        const float* __restrict__ er,
                                                        const int* __restrict__ row_off,
                                                        const float* __restrict__ bias,
                                                        float* __restrict__ out){
    int n    = blockIdx.x * 4 + (threadIdx.x >> 6);
    int lane = threadIdx.x & 63;        // cols 2*lane, 2*lane+1
    int h    = lane >> 4;               // head = (2*lane)/32
    int beg  = row_off[n], end = row_off[n + 1];
    float4 ern = *(const float4*)(er + (size_t)n * NHEAD);

    float a0 = 0.f, a1 = 0.f, ws = 0.f;
    for (int base = beg; base < end; base += 64){
        int cnt = end - base; if (cnt > 64) cnt = 64;
        int   s_l = 0;
        float w0l = 0.f, w1l = 0.f, w2l = 0.f, w3l = 0.f;
        if (lane < cnt){
            s_l = csr_src[base + lane];
            float4 elv = *(const float4*)(el + (size_t)s_l * NHEAD);
            w0l = __expf(lrelu(elv.x + ern.x));
            w1l = __expf(lrelu(elv.y + ern.y));
            w2l = __expf(lrelu(elv.z + ern.z));
            w3l = __expf(lrelu(elv.w + ern.w));
        }
#pragma unroll 4
        for (int j = 0; j < cnt; ++j){
            int s = __shfl(s_l, j, 64);
            float w0 = __shfl(w0l, j, 64);
            float w1 = __shfl(w1l, j, 64);
            float w2 = __shfl(w2l, j, 64);
            float w3 = __shfl(w3l, j, 64);
            float w = (h == 0) ? w0 : (h == 1) ? w1 : (h == 2) ? w2 : w3;
            unsigned int f = *(const unsigned int*)(ftb + (size_t)s * HD + 2 * lane);
            a0 += w * bflo(f);
            a1 += w * bfhi(f);
            ws += w;
        }
    }
    float inv = (end > beg) ? 1.f / ws : 0.f;
    float2 o;
    o.x = a0 * inv + bias[2 * lane + 0];
    o.y = a1 * inv + bias[2 * lane + 1];
    *(float2*)(out + (size_t)n * HD + 2 * lane) = o;
}

extern "C" void kernel_launch(void* const* d_in, const int* in_sizes, int n_in,
                              void* d_out, int out_size, void* d_ws, size_t ws_size,
                              hipStream_t stream){
    const float* feat   = (const float*)d_in[0];
    const int*   src    = (const int*)  d_in[1];
    const int*   dst    = (const int*)  d_in[2];
    const float* W      = (const float*)d_in[3];
    const float* attn_l = (const float*)d_in[4];
    const float* attn_r = (const float*)d_in[5];
    const float* bias   = (const float*)d_in[6];
    float* out = (float*)d_out;
    char*  ws  = (char*)d_ws;

    // workspace layout (bytes)
    unsigned short* ftb = (unsigned short*)(ws + 0);   // 12,800,000
    float* el      = (float*)(ws + 12800000);   // 800,000
    float* er      = (float*)(ws + 13600000);   // 800,000
    int*   deg     = (int*)  (ws + 14400000);   // 200,000
    int*   rank    = (int*)  (ws + 14600000);   // 3,200,000
    int*   row_off = (int*)  (ws + 17800000);   // 200,004 (pad to 200,064)
    int*   csr_src = (int*)  (ws + 18000064);   // 3,200,000   (total ~21.2 MB)

    // transient aliases (used only BEFORE csr_src is written, after gemm for blk_*):
    unsigned short* Wt_hi = (unsigned short*)csr_src;          // 65,536 B (gemm-time only)
    unsigned short* Wt_lo = Wt_hi + 32768;                     // 65,536 B
    int* blk_sums = (int*)(((char*)csr_src) + 131072);         // scan-time only
    int* blk_off  = blk_sums + 256;

    zero_ints<<<(N_NODES + 255) / 256, 256, 0, stream>>>(deg, N_NODES);
    wsplit_kernel<<<128, 256, 0, stream>>>(W, Wt_hi, Wt_lo);
    gemm_kernel<<<(N_NODES + 127) / 128, 256, 0, stream>>>(feat, Wt_hi, Wt_lo,
                                                           attn_l, attn_r, ftb, el, er);
    degree_kernel<<<(N_EDGES + 255) / 256, 256, 0, stream>>>(dst, deg, rank);
    scan_part<<<NB_SCAN, 256, 0, stream>>>(deg, row_off, blk_sums);
    scan_mid<<<1, 256, 0, stream>>>(blk_sums, blk_off);
    scan_add<<<NB_SCAN, 256, 0, stream>>>(row_off, blk_off);
    scatter_kernel<<<(N_EDGES + 255) / 256, 256, 0, stream>>>(src, dst, rank, row_off, csr_src);
    aggregate_kernel<<<(N_NODES + 3) / 4, 256, 0, stream>>>(ftb, csr_src, el, er,
                                                            row_off, bias, out);
}

// Round 6
// 225.197 us; speedup vs baseline: 1.8585x; 1.1015x over previous
//
#include <hip/hip_runtime.h>
#include <hip/hip_bf16.h>
#include <math.h>

#define N_NODES 50000
#define N_EDGES 800000
#define IN_F 256
#define HD 128   // H*D
#define NHEAD 4
#define NB_SCAN 196   // ceil(50000/256)

typedef __attribute__((ext_vector_type(8))) short bf16x8;
typedef __attribute__((ext_vector_type(4))) float f32x4;

__device__ __forceinline__ float lrelu(float x){ return x > 0.f ? x : 0.2f * x; }

__device__ __forceinline__ unsigned short f32_to_bf16_rn(float x){
    union { float f; unsigned int u; } v; v.f = x;
    unsigned int r = v.u + 0x7FFFu + ((v.u >> 16) & 1u);
    return (unsigned short)(r >> 16);
}
__device__ __forceinline__ float bf16_to_f32(unsigned short h){
    union { unsigned int u; float f; } v; v.u = ((unsigned int)h) << 16;
    return v.f;
}
__device__ __forceinline__ float bflo(unsigned int u){
    union { unsigned int x; float f; } v; v.x = u << 16; return v.f;
}
__device__ __forceinline__ float bfhi(unsigned int u){
    union { unsigned int x; float f; } v; v.x = u & 0xFFFF0000u; return v.f;
}

__global__ void zero_ints(int* __restrict__ p, int n){
    int i = blockIdx.x * blockDim.x + threadIdx.x;
    if (i < n) p[i] = 0;
}

// ---------------- W pre-transpose + bf16 hi/lo split: Wt[n][k] ----------------
__global__ __launch_bounds__(256) void wsplit_kernel(const float* __restrict__ W,
                                                     unsigned short* __restrict__ Wt_hi,
                                                     unsigned short* __restrict__ Wt_lo){
    int gid = blockIdx.x * 256 + threadIdx.x;   // 128*256 = 32768 total
    int n = gid >> 8;           // 0..127
    int k = gid & 255;          // 0..255
    float x = W[(size_t)k * HD + n];
    unsigned short h = f32_to_bf16_rn(x);
    float r = x - bf16_to_f32(h);
    unsigned short l = f32_to_bf16_rn(r);
    Wt_hi[gid] = h;
    Wt_lo[gid] = l;
}

// ---------------- GEMM: ftb[N,128](bf16) = feat[N,256] @ W[256,128], fused el/er ----------------
__global__ __launch_bounds__(256) void gemm_kernel(const float* __restrict__ feat,
                                                   const unsigned short* __restrict__ Wt_hi,
                                                   const unsigned short* __restrict__ Wt_lo,
                                                   const float* __restrict__ attn_l,
                                                   const float* __restrict__ attn_r,
                                                   unsigned short* __restrict__ ftb,
                                                   float* __restrict__ el,
                                                   float* __restrict__ er){
    __shared__ unsigned short Ah[128][72];
    __shared__ unsigned short Al[128][72];
    __shared__ unsigned short Bh[128][72];
    __shared__ unsigned short Bl[128][72];

    const int tid  = threadIdx.x;
    const int lane = tid & 63;
    const int wave = tid >> 6;          // 0..3
    const int wrow = wave * 32;
    const int lrow = lane & 15;
    const int lkh  = (lane >> 4) * 8;   // k sub-offset within 32
    const int row0 = blockIdx.x * 128;

    f32x4 acc[2][8];
#pragma unroll
    for (int i = 0; i < 2; i++)
#pragma unroll
        for (int j = 0; j < 8; j++) acc[i][j] = (f32x4){0.f, 0.f, 0.f, 0.f};

    const int srow = tid >> 1;          // 0..127
    const int skh  = (tid & 1) * 32;    // 0 or 32

    for (int kc = 0; kc < 4; ++kc){
        const int k0 = kc * 64;
        // ---- stage A (f32 -> bf16 hi/lo) ----
        {
            int gr = row0 + srow;
            const float* fp = feat + (size_t)gr * IN_F + k0 + skh;
            unsigned short* ah = &Ah[srow][skh];
            unsigned short* al = &Al[srow][skh];
#pragma unroll
            for (int u = 0; u < 8; ++u){
                float4 v = make_float4(0.f,0.f,0.f,0.f);
                if (gr < N_NODES) v = *(const float4*)(fp + 4 * u);
                ushort4 h, l;
                h.x = f32_to_bf16_rn(v.x); l.x = f32_to_bf16_rn(v.x - bf16_to_f32(h.x));
                h.y = f32_to_bf16_rn(v.y); l.y = f32_to_bf16_rn(v.y - bf16_to_f32(h.y));
                h.z = f32_to_bf16_rn(v.z); l.z = f32_to_bf16_rn(v.z - bf16_to_f32(h.z));
                h.w = f32_to_bf16_rn(v.w); l.w = f32_to_bf16_rn(v.w - bf16_to_f32(h.w));
                *(ushort4*)(ah + 4 * u) = h;
                *(ushort4*)(al + 4 * u) = l;
            }
        }
        // ---- stage B (precomputed bf16 hi/lo, Wt[n][k]) ----
        {
            const unsigned short* bh = Wt_hi + srow * 256 + k0 + skh;
            const unsigned short* bl = Wt_lo + srow * 256 + k0 + skh;
#pragma unroll
            for (int u = 0; u < 4; ++u){
                *(uint4*)(&Bh[srow][skh + 8 * u]) = *(const uint4*)(bh + 8 * u);
                *(uint4*)(&Bl[srow][skh + 8 * u]) = *(const uint4*)(bl + 8 * u);
            }
        }
        __syncthreads();
        // ---- compute ----
#pragma unroll
        for (int kk = 0; kk < 2; ++kk){
            const int kb = kk * 32 + lkh;
            bf16x8 ah0 = *(const bf16x8*)(&Ah[wrow + lrow][kb]);
            bf16x8 ah1 = *(const bf16x8*)(&Ah[wrow + 16 + lrow][kb]);
            bf16x8 al0 = *(const bf16x8*)(&Al[wrow + lrow][kb]);
            bf16x8 al1 = *(const bf16x8*)(&Al[wrow + 16 + lrow][kb]);
#pragma unroll
            for (int nf = 0; nf < 8; ++nf){
                bf16x8 bh = *(const bf16x8*)(&Bh[nf * 16 + lrow][kb]);
                bf16x8 bl = *(const bf16x8*)(&Bl[nf * 16 + lrow][kb]);
                acc[0][nf] = __builtin_amdgcn_mfma_f32_16x16x32_bf16(ah0, bh, acc[0][nf], 0, 0, 0);
                acc[1][nf] = __builtin_amdgcn_mfma_f32_16x16x32_bf16(ah1, bh, acc[1][nf], 0, 0, 0);
                acc[0][nf] = __builtin_amdgcn_mfma_f32_16x16x32_bf16(ah0, bl, acc[0][nf], 0, 0, 0);
                acc[1][nf] = __builtin_amdgcn_mfma_f32_16x16x32_bf16(ah1, bl, acc[1][nf], 0, 0, 0);
                acc[0][nf] = __builtin_amdgcn_mfma_f32_16x16x32_bf16(al0, bh, acc[0][nf], 0, 0, 0);
                acc[1][nf] = __builtin_amdgcn_mfma_f32_16x16x32_bf16(al1, bh, acc[1][nf], 0, 0, 0);
            }
        }
        __syncthreads();
    }
    // ---- epilogue: C/D layout col=lrow+nf*16, row=wrow+mf*16+(lane>>4)*4+r ----
    float alv[8], arv[8];
#pragma unroll
    for (int nf = 0; nf < 8; ++nf){
        alv[nf] = attn_l[lrow + nf * 16];
        arv[nf] = attn_r[lrow + nf * 16];
    }
#pragma unroll
    for (int mf = 0; mf < 2; ++mf){
#pragma unroll
        for (int r = 0; r < 4; ++r){
            int gr = row0 + wrow + mf * 16 + (lane >> 4) * 4 + r;
            if (gr < N_NODES){
                unsigned short* op = ftb + (size_t)gr * HD + lrow;
#pragma unroll
                for (int nf = 0; nf < 8; ++nf) op[nf * 16] = f32_to_bf16_rn(acc[mf][nf][r]);
            }
            float pl0 = acc[mf][0][r] * alv[0] + acc[mf][1][r] * alv[1];
            float pl1 = acc[mf][2][r] * alv[2] + acc[mf][3][r] * alv[3];
            float pl2 = acc[mf][4][r] * alv[4] + acc[mf][5][r] * alv[5];
            float pl3 = acc[mf][6][r] * alv[6] + acc[mf][7][r] * alv[7];
            float pr0 = acc[mf][0][r] * arv[0] + acc[mf][1][r] * arv[1];
            float pr1 = acc[mf][2][r] * arv[2] + acc[mf][3][r] * arv[3];
            float pr2 = acc[mf][4][r] * arv[4] + acc[mf][5][r] * arv[5];
            float pr3 = acc[mf][6][r] * arv[6] + acc[mf][7][r] * arv[7];
#pragma unroll
            for (int m = 1; m <= 8; m <<= 1){
                pl0 += __shfl_xor(pl0, m, 64); pl1 += __shfl_xor(pl1, m, 64);
                pl2 += __shfl_xor(pl2, m, 64); pl3 += __shfl_xor(pl3, m, 64);
                pr0 += __shfl_xor(pr0, m, 64); pr1 += __shfl_xor(pr1, m, 64);
                pr2 += __shfl_xor(pr2, m, 64); pr3 += __shfl_xor(pr3, m, 64);
            }
            if ((lane & 15) == 0 && gr < N_NODES){
                *(float4*)(el + (size_t)gr * NHEAD) = make_float4(pl0, pl1, pl2, pl3);
                *(float4*)(er + (size_t)gr * NHEAD) = make_float4(pr0, pr1, pr2, pr3);
            }
        }
    }
}

// ---------------- CSR build: degree + rank in one pass ----------------
__global__ void degree_kernel(const int* __restrict__ dst, int* __restrict__ deg,
                              int* __restrict__ rank){
    int e = blockIdx.x * blockDim.x + threadIdx.x;
    if (e < N_EDGES) rank[e] = atomicAdd(&deg[dst[e]], 1);
}

// hierarchical scan: part -> mid -> add
__global__ __launch_bounds__(256) void scan_part(const int* __restrict__ deg,
                                                 int* __restrict__ row_off,
                                                 int* __restrict__ blk_sums){
    __shared__ int lds[256];
    int tid = threadIdx.x;
    int i = blockIdx.x * 256 + tid;
    int v = (i < N_NODES) ? deg[i] : 0;
    int x = v;
    lds[tid] = x;
    __syncthreads();
    for (int off = 1; off < 256; off <<= 1){
        int t = (tid >= off) ? lds[tid - off] : 0;
        __syncthreads();
        x += t;
        lds[tid] = x;
        __syncthreads();
    }
    if (i < N_NODES) row_off[i] = x - v;          // local exclusive
    if (tid == 255) blk_sums[blockIdx.x] = x;     // block total
}

__global__ __launch_bounds__(256) void scan_mid(int* __restrict__ blk_sums,
                                                int* __restrict__ blk_off){
    __shared__ int lds[256];
    int tid = threadIdx.x;
    int v = (tid < NB_SCAN) ? blk_sums[tid] : 0;
    int x = v;
    lds[tid] = x;
    __syncthreads();
    for (int off = 1; off < 256; off <<= 1){
        int t = (tid >= off) ? lds[tid - off] : 0;
        __syncthreads();
        x += t;
        lds[tid] = x;
        __syncthreads();
    }
    blk_off[tid] = x - v;                          // exclusive
}

__global__ __launch_bounds__(256) void scan_add(int* __restrict__ row_off,
                                                const int* __restrict__ blk_off){
    int i = blockIdx.x * 256 + threadIdx.x;
    if (i < N_NODES) row_off[i] += blk_off[blockIdx.x];
    if (blockIdx.x == 0 && threadIdx.x == 0) row_off[N_NODES] = N_EDGES;
}

// ---------------- scatter: atomic-free, 4B per edge ----------------
__global__ void scatter_kernel(const int* __restrict__ src, const int* __restrict__ dst,
                               const int* __restrict__ rank, const int* __restrict__ row_off,
                               int* __restrict__ csr_src){
    int e = blockIdx.x * blockDim.x + threadIdx.x;
    if (e >= N_EDGES) return;
    csr_src[row_off[dst[e]] + rank[e]] = src[e];
}

// ---------------- aggregation: 4 nodes/block (1 wave each), 4 edges in flight ----------------
// wave split: g = lane>>4 picks edge j0+g; l = lane&15 covers cols 8l..8l+7 (16B dwordx4);
// head for those cols: h = l>>2. Per-chunk weights staged in per-wave LDS (no block barrier:
// LDS completes in-order within a wave; asm waitcnt + sched_barrier pin the ordering).
__global__ __launch_bounds__(256) void aggregate_kernel(const unsigned short* __restrict__ ftb,
                                                        const int* __restrict__ csr_src,
                                                        const float* __restrict__ el,
                                                        const float* __restrict__ er,
                                                        const int* __restrict__ row_off,
                                                        const float* __restrict__ bias,
                                                        float* __restrict__ out){
    __shared__ float lw[4][64][4];   // [wave][edge-in-chunk][head]
    __shared__ int   ls[4][64];      // [wave][edge-in-chunk]

    const int wv   = threadIdx.x >> 6;
    const int n    = blockIdx.x * 4 + wv;
    const int lane = threadIdx.x & 63;
    const int g    = lane >> 4;      // edge subgroup 0..3
    const int l    = lane & 15;      // 16B chunk within row
    const int h    = l >> 2;         // head of cols 8l..8l+7
    const int beg  = row_off[n], end = row_off[n + 1];
    const float4 ern = *(const float4*)(er + (size_t)n * NHEAD);

    float a[8];
#pragma unroll
    for (int k = 0; k < 8; ++k) a[k] = 0.f;
    float wsum = 0.f;

    for (int base = beg; base < end; base += 64){
        int cnt = end - base; if (cnt > 64) cnt = 64;
        // ---- stage this chunk's weights + src ids into per-wave LDS ----
        float4 w4 = make_float4(0.f, 0.f, 0.f, 0.f);
        int s_l = 0;
        if (lane < cnt){
            s_l = csr_src[base + lane];
            float4 elv = *(const float4*)(el + (size_t)s_l * NHEAD);
            w4.x = __expf(lrelu(elv.x + ern.x));
            w4.y = __expf(lrelu(elv.y + ern.y));
            w4.z = __expf(lrelu(elv.z + ern.z));
            w4.w = __expf(lrelu(elv.w + ern.w));
        }
        ls[wv][lane] = s_l;
        *(float4*)(&lw[wv][lane][0]) = w4;
        asm volatile("s_waitcnt lgkmcnt(0)" ::: "memory");
        __builtin_amdgcn_sched_barrier(0);
        // ---- 4 edges in flight: group g takes edge j0+g ----
        for (int j0 = 0; j0 < cnt; j0 += 4){
            int j = j0 + g;                       // may exceed cnt on tail: w=0, s=0 -> no-op
            float w = lw[wv][j][h];
            int   s = ls[wv][j];
            uint4 f = *(const uint4*)(ftb + (size_t)s * HD + 8 * l);
            a[0] += w * bflo(f.x); a[1] += w * bfhi(f.x);
            a[2] += w * bflo(f.y); a[3] += w * bfhi(f.y);
            a[4] += w * bflo(f.z); a[5] += w * bfhi(f.z);
            a[6] += w * bflo(f.w); a[7] += w * bfhi(f.w);
            wsum += w;
        }
        __builtin_amdgcn_sched_barrier(0);        // keep next chunk's ds_write after these reads
    }
    // ---- reduce across the 4 edge-groups (lanes l, l+16, l+32, l+48 hold same cols) ----
#pragma unroll
    for (int m = 16; m <= 32; m <<= 1){
#pragma unroll
        for (int k = 0; k < 8; ++k) a[k] += __shfl_xor(a[k], m, 64);
        wsum += __shfl_xor(wsum, m, 64);
    }
    float inv = (end > beg) ? 1.f / wsum : 0.f;
    if (g < 2){
        int col = 8 * l + 4 * g;
        float4 b4 = *(const float4*)(bias + col);
        float4 o;
        o.x = a[4 * g + 0] * inv + b4.x;
        o.y = a[4 * g + 1] * inv + b4.y;
        o.z = a[4 * g + 2] * inv + b4.z;
        o.w = a[4 * g + 3] * inv + b4.w;
        *(float4*)(out + (size_t)n * HD + col) = o;
    }
}

extern "C" void kernel_launch(void* const* d_in, const int* in_sizes, int n_in,
                              void* d_out, int out_size, void* d_ws, size_t ws_size,
                              hipStream_t stream){
    const float* feat   = (const float*)d_in[0];
    const int*   src    = (const int*)  d_in[1];
    const int*   dst    = (const int*)  d_in[2];
    const float* W      = (const float*)d_in[3];
    const float* attn_l = (const float*)d_in[4];
    const float* attn_r = (const float*)d_in[5];
    const float* bias   = (const float*)d_in[6];
    float* out = (float*)d_out;
    char*  ws  = (char*)d_ws;

    // workspace layout (bytes)
    unsigned short* ftb = (unsigned short*)(ws + 0);   // 12,800,000
    float* el      = (float*)(ws + 12800000);   // 800,000
    float* er      = (float*)(ws + 13600000);   // 800,000
    int*   deg     = (int*)  (ws + 14400000);   // 200,000
    int*   rank    = (int*)  (ws + 14600000);   // 3,200,000
    int*   row_off = (int*)  (ws + 17800000);   // 200,004 (pad to 200,064)
    int*   csr_src = (int*)  (ws + 18000064);   // 3,200,000   (total ~21.2 MB)

    // transient aliases (used only BEFORE csr_src is written):
    unsigned short* Wt_hi = (unsigned short*)csr_src;          // 65,536 B (gemm-time only)
    unsigned short* Wt_lo = Wt_hi + 32768;                     // 65,536 B
    int* blk_sums = (int*)(((char*)csr_src) + 131072);         // scan-time only
    int* blk_off  = blk_sums + 256;

    zero_ints<<<(N_NODES + 255) / 256, 256, 0, stream>>>(deg, N_NODES);
    wsplit_kernel<<<128, 256, 0, stream>>>(W, Wt_hi, Wt_lo);
    gemm_kernel<<<(N_NODES + 127) / 128, 256, 0, stream>>>(feat, Wt_hi, Wt_lo,
                                                           attn_l, attn_r, ftb, el, er);
    degree_kernel<<<(N_EDGES + 255) / 256, 256, 0, stream>>>(dst, deg, rank);
    scan_part<<<NB_SCAN, 256, 0, stream>>>(deg, row_off, blk_sums);
    scan_mid<<<1, 256, 0, stream>>>(blk_sums, blk_off);
    scan_add<<<NB_SCAN, 256, 0, stream>>>(row_off, blk_off);
    scatter_kernel<<<(N_EDGES + 255) / 256, 256, 0, stream>>>(src, dst, rank, row_off, csr_src);
    aggregate_kernel<<<(N_NODES + 3) / 4, 256, 0, stream>>>(ftb, csr_src, el, er,
                                                            row_off, bias, out);
}

// Round 7
// 222.795 us; speedup vs baseline: 1.8785x; 1.0108x over previous
//
#include <hip/hip_runtime.h>
#include <hip/hip_bf16.h>
#include <math.h>

#define N_NODES 50000
#define N_EDGES 800000
#define IN_F 256
#define HD 128   // H*D
#define NHEAD 4
#define NB_SCAN 196   // ceil(50000/256)
#define GBM 64        // GEMM rows per block

typedef __attribute__((ext_vector_type(8))) short bf16x8;
typedef __attribute__((ext_vector_type(4))) float f32x4;

__device__ __forceinline__ float lrelu(float x){ return x > 0.f ? x : 0.2f * x; }

__device__ __forceinline__ unsigned short f32_to_bf16_rn(float x){
    union { float f; unsigned int u; } v; v.f = x;
    unsigned int r = v.u + 0x7FFFu + ((v.u >> 16) & 1u);
    return (unsigned short)(r >> 16);
}
__device__ __forceinline__ float bf16_to_f32(unsigned short h){
    union { unsigned int u; float f; } v; v.u = ((unsigned int)h) << 16;
    return v.f;
}
__device__ __forceinline__ float bflo(unsigned int u){
    union { unsigned int x; float f; } v; v.x = u << 16; return v.f;
}
__device__ __forceinline__ float bfhi(unsigned int u){
    union { unsigned int x; float f; } v; v.x = u & 0xFFFF0000u; return v.f;
}

__global__ void zero_ints(int* __restrict__ p, int n){
    int i = blockIdx.x * blockDim.x + threadIdx.x;
    if (i < n) p[i] = 0;
}

// ---------------- W pre-transpose + bf16 hi/lo split: Wt[n][k] ----------------
__global__ __launch_bounds__(256) void wsplit_kernel(const float* __restrict__ W,
                                                     unsigned short* __restrict__ Wt_hi,
                                                     unsigned short* __restrict__ Wt_lo){
    int gid = blockIdx.x * 256 + threadIdx.x;   // 128*256 = 32768 total
    int n = gid >> 8;           // 0..127
    int k = gid & 255;          // 0..255
    float x = W[(size_t)k * HD + n];
    unsigned short h = f32_to_bf16_rn(x);
    float r = x - bf16_to_f32(h);
    unsigned short l = f32_to_bf16_rn(r);
    Wt_hi[gid] = h;
    Wt_lo[gid] = l;
}

// ---------------- GEMM: ftb[N,128](bf16) = feat[N,256] @ W[256,128], fused el/er ----------------
// 256 thr = 4 waves; wave owns 16 rows (one m-frag), all 8 n-frags.
// A: direct global->reg (f32 -> bf16 hi/lo in regs). B: frag-major LDS (conflict-free b128).
__global__ __launch_bounds__(256, 4) void gemm_kernel(const float* __restrict__ feat,
                                                      const unsigned short* __restrict__ Wt_hi,
                                                      const unsigned short* __restrict__ Wt_lo,
                                                      const float* __restrict__ attn_l,
                                                      const float* __restrict__ attn_r,
                                                      unsigned short* __restrict__ ftb,
                                                      float* __restrict__ el,
                                                      float* __restrict__ er){
    __shared__ unsigned short Bh[2][8][64][8];   // [kb][nf][lane][8] = 16KB
    __shared__ unsigned short Bl[2][8][64][8];   // 16KB

    const int tid  = threadIdx.x;
    const int lane = tid & 63;
    const int wv   = tid >> 6;            // 0..3
    const int r    = lane & 15;           // A-frag row within m16 tile
    const int g    = lane >> 4;           // k-subgroup 0..3
    const int arow = blockIdx.x * GBM + wv * 16 + r;     // this lane's A source row
    const bool rowok = (arow < N_NODES);
    const float* arp = feat + (size_t)arow * IN_F + g * 8;

    f32x4 acc[8];
#pragma unroll
    for (int j = 0; j < 8; ++j) acc[j] = (f32x4){0.f, 0.f, 0.f, 0.f};

    for (int kc = 0; kc < 4; ++kc){
        const int k0 = kc * 64;
        // ---- stage B frag-major: unit u = (kb*8+nf)*64 + l2 ; thread covers u = tid*4..tid*4+3 ----
#pragma unroll
        for (int i = 0; i < 4; ++i){
            int u  = tid * 4 + i;
            int l2 = u & 63;
            int fn = (u >> 6) & 7;
            int kb = u >> 9;
            int nn = fn * 16 + (l2 & 15);
            int kk = k0 + kb * 32 + (l2 >> 4) * 8;
            *(uint4*)(&Bh[kb][fn][l2][0]) = *(const uint4*)(Wt_hi + nn * 256 + kk);
            *(uint4*)(&Bl[kb][fn][l2][0]) = *(const uint4*)(Wt_lo + nn * 256 + kk);
        }
        __syncthreads();
#pragma unroll
        for (int kb = 0; kb < 2; ++kb){
            // ---- A frag: 8 f32 -> bf16 hi/lo in regs ----
            float4 v0 = make_float4(0.f, 0.f, 0.f, 0.f), v1 = v0;
            if (rowok){
                const float* fp = arp + k0 + kb * 32;
                v0 = *(const float4*)(fp);
                v1 = *(const float4*)(fp + 4);
            }
            float av[8] = {v0.x, v0.y, v0.z, v0.w, v1.x, v1.y, v1.z, v1.w};
            bf16x8 ah, al;
#pragma unroll
            for (int j = 0; j < 8; ++j){
                unsigned short h = f32_to_bf16_rn(av[j]);
                ah[j] = (short)h;
                al[j] = (short)f32_to_bf16_rn(av[j] - bf16_to_f32(h));
            }
#pragma unroll
            for (int nf = 0; nf < 8; ++nf){
                bf16x8 bh = *(const bf16x8*)(&Bh[kb][nf][lane][0]);
                bf16x8 bl = *(const bf16x8*)(&Bl[kb][nf][lane][0]);
                acc[nf] = __builtin_amdgcn_mfma_f32_16x16x32_bf16(ah, bh, acc[nf], 0, 0, 0);
                acc[nf] = __builtin_amdgcn_mfma_f32_16x16x32_bf16(ah, bl, acc[nf], 0, 0, 0);
                acc[nf] = __builtin_amdgcn_mfma_f32_16x16x32_bf16(al, bh, acc[nf], 0, 0, 0);
            }
        }
        __syncthreads();
    }
    // ---- epilogue: C/D layout col=(lane&15)+nf*16, row=wv*16+(lane>>4)*4+reg ----
    float alv[8], arv[8];
#pragma unroll
    for (int nf = 0; nf < 8; ++nf){
        alv[nf] = attn_l[r + nf * 16];
        arv[nf] = attn_r[r + nf * 16];
    }
    const int g4 = g * 4;
#pragma unroll
    for (int rg = 0; rg < 4; ++rg){
        int gr = blockIdx.x * GBM + wv * 16 + g4 + rg;
        if (gr < N_NODES){
            unsigned short* op = ftb + (size_t)gr * HD + r;
#pragma unroll
            for (int nf = 0; nf < 8; ++nf) op[nf * 16] = f32_to_bf16_rn(acc[nf][rg]);
        }
        float pl0 = acc[0][rg] * alv[0] + acc[1][rg] * alv[1];
        float pl1 = acc[2][rg] * alv[2] + acc[3][rg] * alv[3];
        float pl2 = acc[4][rg] * alv[4] + acc[5][rg] * alv[5];
        float pl3 = acc[6][rg] * alv[6] + acc[7][rg] * alv[7];
        float pr0 = acc[0][rg] * arv[0] + acc[1][rg] * arv[1];
        float pr1 = acc[2][rg] * arv[2] + acc[3][rg] * arv[3];
        float pr2 = acc[4][rg] * arv[4] + acc[5][rg] * arv[5];
        float pr3 = acc[6][rg] * arv[6] + acc[7][rg] * arv[7];
#pragma unroll
        for (int m = 1; m <= 8; m <<= 1){
            pl0 += __shfl_xor(pl0, m, 64); pl1 += __shfl_xor(pl1, m, 64);
            pl2 += __shfl_xor(pl2, m, 64); pl3 += __shfl_xor(pl3, m, 64);
            pr0 += __shfl_xor(pr0, m, 64); pr1 += __shfl_xor(pr1, m, 64);
            pr2 += __shfl_xor(pr2, m, 64); pr3 += __shfl_xor(pr3, m, 64);
        }
        if (r == 0 && gr < N_NODES){
            *(float4*)(el + (size_t)gr * NHEAD) = make_float4(pl0, pl1, pl2, pl3);
            *(float4*)(er + (size_t)gr * NHEAD) = make_float4(pr0, pr1, pr2, pr3);
        }
    }
}

// ---------------- CSR build: degree + rank in one pass ----------------
__global__ void degree_kernel(const int* __restrict__ dst, int* __restrict__ deg,
                              int* __restrict__ rank){
    int e = blockIdx.x * blockDim.x + threadIdx.x;
    if (e < N_EDGES) rank[e] = atomicAdd(&deg[dst[e]], 1);
}

// hierarchical scan: part -> mid -> add
__global__ __launch_bounds__(256) void scan_part(const int* __restrict__ deg,
                                                 int* __restrict__ row_off,
                                                 int* __restrict__ blk_sums){
    __shared__ int lds[256];
    int tid = threadIdx.x;
    int i = blockIdx.x * 256 + tid;
    int v = (i < N_NODES) ? deg[i] : 0;
    int x = v;
    lds[tid] = x;
    __syncthreads();
    for (int off = 1; off < 256; off <<= 1){
        int t = (tid >= off) ? lds[tid - off] : 0;
        __syncthreads();
        x += t;
        lds[tid] = x;
        __syncthreads();
    }
    if (i < N_NODES) row_off[i] = x - v;          // local exclusive
    if (tid == 255) blk_sums[blockIdx.x] = x;     // block total
}

__global__ __launch_bounds__(256) void scan_mid(int* __restrict__ blk_sums,
                                                int* __restrict__ blk_off){
    __shared__ int lds[256];
    int tid = threadIdx.x;
    int v = (tid < NB_SCAN) ? blk_sums[tid] : 0;
    int x = v;
    lds[tid] = x;
    __syncthreads();
    for (int off = 1; off < 256; off <<= 1){
        int t = (tid >= off) ? lds[tid - off] : 0;
        __syncthreads();
        x += t;
        lds[tid] = x;
        __syncthreads();
    }
    blk_off[tid] = x - v;                          // exclusive
}

__global__ __launch_bounds__(256) void scan_add(int* __restrict__ row_off,
                                                const int* __restrict__ blk_off){
    int i = blockIdx.x * 256 + threadIdx.x;
    if (i < N_NODES) row_off[i] += blk_off[blockIdx.x];
    if (blockIdx.x == 0 && threadIdx.x == 0) row_off[N_NODES] = N_EDGES;
}

// ---------------- scatter: atomic-free, 4B per edge ----------------
__global__ void scatter_kernel(const int* __restrict__ src, const int* __restrict__ dst,
                               const int* __restrict__ rank, const int* __restrict__ row_off,
                               int* __restrict__ csr_src){
    int e = blockIdx.x * blockDim.x + threadIdx.x;
    if (e >= N_EDGES) return;
    csr_src[row_off[dst[e]] + rank[e]] = src[e];
}

// ---------------- aggregation: 4 nodes/block (1 wave each), 4 edges in flight ----------------
__global__ __launch_bounds__(256) void aggregate_kernel(const unsigned short* __restrict__ ftb,
                                                        const int* __restrict__ csr_src,
                                                        const float* __restrict__ el,
                                                        const float* __restrict__ er,
                                                        const int* __restrict__ row_off,
                                                        const float* __restrict__ bias,
                                                        float* __restrict__ out){
    __shared__ float lw[4][64][4];   // [wave][edge-in-chunk][head]
    __shared__ int   ls[4][64];      // [wave][edge-in-chunk]

    const int wv   = threadIdx.x >> 6;
    const int n    = blockIdx.x * 4 + wv;
    const int lane = threadIdx.x & 63;
    const int g    = lane >> 4;      // edge subgroup 0..3
    const int l    = lane & 15;      // 16B chunk within row
    const int h    = l >> 2;         // head of cols 8l..8l+7
    const int beg  = row_off[n], end = row_off[n + 1];
    const float4 ern = *(const float4*)(er + (size_t)n * NHEAD);

    float a[8];
#pragma unroll
    for (int k = 0; k < 8; ++k) a[k] = 0.f;
    float wsum = 0.f;

    for (int base = beg; base < end; base += 64){
        int cnt = end - base; if (cnt > 64) cnt = 64;
        // ---- stage this chunk's weights + src ids into per-wave LDS ----
        float4 w4 = make_float4(0.f, 0.f, 0.f, 0.f);
        int s_l = 0;
        if (lane < cnt){
            s_l = csr_src[base + lane];
            float4 elv = *(const float4*)(el + (size_t)s_l * NHEAD);
            w4.x = __expf(lrelu(elv.x + ern.x));
            w4.y = __expf(lrelu(elv.y + ern.y));
            w4.z = __expf(lrelu(elv.z + ern.z));
            w4.w = __expf(lrelu(elv.w + ern.w));
        }
        ls[wv][lane] = s_l;
        *(float4*)(&lw[wv][lane][0]) = w4;
        asm volatile("s_waitcnt lgkmcnt(0)" ::: "memory");
        __builtin_amdgcn_sched_barrier(0);
        // ---- 4 edges in flight: group g takes edge j0+g ----
        for (int j0 = 0; j0 < cnt; j0 += 4){
            int j = j0 + g;                       // may exceed cnt on tail: w=0, s=0 -> no-op
            float w = lw[wv][j][h];
            int   s = ls[wv][j];
            uint4 f = *(const uint4*)(ftb + (size_t)s * HD + 8 * l);
            a[0] += w * bflo(f.x); a[1] += w * bfhi(f.x);
            a[2] += w * bflo(f.y); a[3] += w * bfhi(f.y);
            a[4] += w * bflo(f.z); a[5] += w * bfhi(f.z);
            a[6] += w * bflo(f.w); a[7] += w * bfhi(f.w);
            wsum += w;
        }
        __builtin_amdgcn_sched_barrier(0);        // keep next chunk's ds_write after these reads
    }
    // ---- reduce across the 4 edge-groups ----
#pragma unroll
    for (int m = 16; m <= 32; m <<= 1){
#pragma unroll
        for (int k = 0; k < 8; ++k) a[k] += __shfl_xor(a[k], m, 64);
        wsum += __shfl_xor(wsum, m, 64);
    }
    float inv = (end > beg) ? 1.f / wsum : 0.f;
    if (g < 2){
        int col = 8 * l + 4 * g;
        float4 b4 = *(const float4*)(bias + col);
        float4 o;
        o.x = a[4 * g + 0] * inv + b4.x;
        o.y = a[4 * g + 1] * inv + b4.y;
        o.z = a[4 * g + 2] * inv + b4.z;
        o.w = a[4 * g + 3] * inv + b4.w;
        *(float4*)(out + (size_t)n * HD + col) = o;
    }
}

extern "C" void kernel_launch(void* const* d_in, const int* in_sizes, int n_in,
                              void* d_out, int out_size, void* d_ws, size_t ws_size,
                              hipStream_t stream){
    const float* feat   = (const float*)d_in[0];
    const int*   src    = (const int*)  d_in[1];
    const int*   dst    = (const int*)  d_in[2];
    const float* W      = (const float*)d_in[3];
    const float* attn_l = (const float*)d_in[4];
    const float* attn_r = (const float*)d_in[5];
    const float* bias   = (const float*)d_in[6];
    float* out = (float*)d_out;
    char*  ws  = (char*)d_ws;

    // workspace layout (bytes)
    unsigned short* ftb = (unsigned short*)(ws + 0);   // 12,800,000
    float* el      = (float*)(ws + 12800000);   // 800,000
    float* er      = (float*)(ws + 13600000);   // 800,000
    int*   deg     = (int*)  (ws + 14400000);   // 200,000
    int*   rank    = (int*)  (ws + 14600000);   // 3,200,000
    int*   row_off = (int*)  (ws + 17800000);   // 200,004 (pad to 200,064)
    int*   csr_src = (int*)  (ws + 18000064);   // 3,200,000   (total ~21.2 MB)

    // transient aliases (used only BEFORE csr_src is written):
    unsigned short* Wt_hi = (unsigned short*)csr_src;          // 65,536 B (gemm-time only)
    unsigned short* Wt_lo = Wt_hi + 32768;                     // 65,536 B
    int* blk_sums = (int*)(((char*)csr_src) + 131072);         // scan-time only
    int* blk_off  = blk_sums + 256;

    zero_ints<<<(N_NODES + 255) / 256, 256, 0, stream>>>(deg, N_NODES);
    wsplit_kernel<<<128, 256, 0, stream>>>(W, Wt_hi, Wt_lo);
    gemm_kernel<<<(N_NODES + GBM - 1) / GBM, 256, 0, stream>>>(feat, Wt_hi, Wt_lo,
                                                               attn_l, attn_r, ftb, el, er);
    degree_kernel<<<(N_EDGES + 255) / 256, 256, 0, stream>>>(dst, deg, rank);
    scan_part<<<NB_SCAN, 256, 0, stream>>>(deg, row_off, blk_sums);
    scan_mid<<<1, 256, 0, stream>>>(blk_sums, blk_off);
    scan_add<<<NB_SCAN, 256, 0, stream>>>(row_off, blk_off);
    scatter_kernel<<<(N_EDGES + 255) / 256, 256, 0, stream>>>(src, dst, rank, row_off, csr_src);
    aggregate_kernel<<<(N_NODES + 3) / 4, 256, 0, stream>>>(ftb, csr_src, el, er,
                                                            row_off, bias, out);
}